// Round 14
// baseline (623.825 us; speedup 1.0000x reference)
//
#include <hip/hip_runtime.h>

#define LOG2E 1.4426950408889634f

typedef unsigned long long u64;
typedef unsigned int uint;
typedef unsigned short ushort_t;
typedef __attribute__((ext_vector_type(8))) short short8;
typedef __attribute__((ext_vector_type(4))) float floatx4;
typedef __attribute__((ext_vector_type(4))) int intx4;
typedef __attribute__((ext_vector_type(4))) unsigned short ushort4v;

#define GN 4096
#define GH 256
#define KZ 8
#define KSTEPS 16   // K-steps of 32 neighbors per block: KZ*KSTEPS*32 = 4096

__device__ __forceinline__ ushort_t f2bf(float f){
  uint u = __float_as_uint(f);
  u += 0x7FFFu + ((u >> 16) & 1u);
  return (ushort_t)(u >> 16);
}
__device__ __forceinline__ float bf2f(ushort_t h){
  return __uint_as_float(((uint)h) << 16);
}
__device__ __forceinline__ float exp2_(float x){
#if __has_builtin(__builtin_amdgcn_exp2f)
  return __builtin_amdgcn_exp2f(x);
#else
  return exp2f(x);
#endif
}

// ---- fused prep: blocks 0..1023 pack adj (4 rows each); 1024.. transpose W
__global__ __launch_bounds__(256) void prep(const int* __restrict__ adj,
                                            u64* __restrict__ mask,
                                            const float* __restrict__ W1,
                                            ushort_t* __restrict__ W1h,
                                            ushort_t* __restrict__ W1l,
                                            const float* __restrict__ W2,
                                            ushort_t* __restrict__ W2h,
                                            ushort_t* __restrict__ W2l){
  __shared__ union {
    unsigned char nib[4][1024];
    ushort_t tt[2][32][33];
  } sh;
  const int t = threadIdx.x;
  if (blockIdx.x < 1024){
    const int r0 = blockIdx.x * 4;
    const int* base = adj + (size_t)r0 * GN;
    #pragma unroll
    for (int i = 0; i < 16; ++i){
      int c = i * 256 + t;                 // int4 index within 4 rows
      intx4 v = *(const intx4*)(base + c * 4);
      uint n = (uint)(v[0] > 0) | ((uint)(v[1] > 0) << 1) |
               ((uint)(v[2] > 0) << 2) | ((uint)(v[3] > 0) << 3);
      sh.nib[c >> 10][c & 1023] = (unsigned char)n;
    }
    __syncthreads();
    {
      int r = t >> 6, wi = t & 63;
      const u64* p = (const u64*)sh.nib[r];
      u64 x0 = p[wi * 2], x1 = p[wi * 2 + 1];
      auto comp = [](u64 x)->u64{
        x = (x | (x >> 4))  & 0x00FF00FF00FF00FFULL;
        x = (x | (x >> 8))  & 0x0000FFFF0000FFFFULL;
        x = (x | (x >> 16)) & 0x00000000FFFFFFFFULL;
        return x;
      };
      mask[(size_t)(r0 + r) * 64 + wi] = comp(x0) | (comp(x1) << 32);
    }
    return;
  }
  int b = blockIdx.x - 1024;
  const float* in; ushort_t* hi; ushort_t* lo; int R, idx;
  if (b < 128){ in = W1; hi = W1h; lo = W1l; R = 512; idx = b; }
  else        { in = W2; hi = W2h; lo = W2l; R = 256; idx = b - 128; }
  const int C = GH;
  const int bx = idx & 7, by = idx >> 3;
  const int i0 = by * 32, j0 = bx * 32;
  const int r = t >> 3, c4 = (t & 7) * 4;
  floatx4 v = *(const floatx4*)(in + (size_t)(i0 + r) * C + j0 + c4);
  #pragma unroll
  for (int e = 0; e < 4; ++e){
    ushort_t h = f2bf(v[e]);
    sh.tt[0][r][c4 + e] = h;
    sh.tt[1][r][c4 + e] = f2bf(v[e] - bf2f(h));
  }
  __syncthreads();
  ushort4v oh, ol;
  #pragma unroll
  for (int e = 0; e < 4; ++e){ oh[e] = sh.tt[0][c4 + e][r]; ol[e] = sh.tt[1][c4 + e][r]; }
  *(ushort4v*)(hi + (size_t)(j0 + r) * R + i0 + c4) = oh;
  *(ushort4v*)(lo + (size_t)(j0 + r) * R + i0 + c4) = ol;
}

// --- split-bf16 GEMM + fused epilogue: writes bf16 V^T and score-dot partials.
template<bool BN>
__global__ __launch_bounds__(256) void gemm_split(const float* __restrict__ A,
                                                  const ushort_t* __restrict__ BThi,
                                                  const ushort_t* __restrict__ BTlo,
                                                  const float* __restrict__ bnsc,
                                                  const float* __restrict__ bnbi,
                                                  const float* __restrict__ as,
                                                  const float* __restrict__ ad,
                                                  ushort_t* __restrict__ VTh,
                                                  float* __restrict__ spart,
                                                  int K){
  __shared__ short8 AhiV[32 * 8];
  __shared__ short8 AloV[32 * 8];
  __shared__ short8 BhiV[64 * 8];
  __shared__ short8 BloV[64 * 8];
  __shared__ float red[32][2][2];
  char* Ahi = (char*)AhiV; char* Alo = (char*)AloV;
  char* Bhi = (char*)BhiV; char* Blo = (char*)BloV;
  const int tid = threadIdx.x;
  const int i0 = blockIdx.y * 32, n0 = blockIdx.x * 64;
  const int lane = tid & 63, wave = tid >> 6;
  const int wr = wave & 1, wc = wave >> 1;
  const int l15 = lane & 15, lhi = lane >> 4;
  const int rs = tid >> 3, ch = tid & 7;
  floatx4 acc[2] = {};
  for (int kb = 0; kb < K; kb += 64){
    {
      int r = rs;
      floatx4 f0 = *(const floatx4*)(A + (size_t)(i0 + r) * K + kb + ch * 8);
      floatx4 f1 = *(const floatx4*)(A + (size_t)(i0 + r) * K + kb + ch * 8 + 4);
      if constexpr (BN){
        floatx4 sc0 = *(const floatx4*)(bnsc + kb + ch * 8);
        floatx4 sc1 = *(const floatx4*)(bnsc + kb + ch * 8 + 4);
        floatx4 bi0 = *(const floatx4*)(bnbi + kb + ch * 8);
        floatx4 bi1 = *(const floatx4*)(bnbi + kb + ch * 8 + 4);
        #pragma unroll
        for (int e = 0; e < 4; ++e){
          f0[e] = f0[e] * sc0[e] + bi0[e];
          f1[e] = f1[e] * sc1[e] + bi1[e];
        }
      }
      short8 ah, al;
      #pragma unroll
      for (int e = 0; e < 4; ++e){
        ushort_t h0 = f2bf(f0[e]); ah[e] = (short)h0; al[e] = (short)f2bf(f0[e] - bf2f(h0));
        ushort_t h1 = f2bf(f1[e]); ah[e+4] = (short)h1; al[e+4] = (short)f2bf(f1[e] - bf2f(h1));
      }
      const int sw = (ch * 16) ^ ((r & 7) << 4);
      *(short8*)(Ahi + r * 128 + sw) = ah;
      *(short8*)(Alo + r * 128 + sw) = al;
      #pragma unroll
      for (int q = 0; q < 2; ++q){
        int rb = rs + q * 32;
        const int swb = (ch * 16) ^ ((rb & 7) << 4);
        short8 bh = *(const short8*)(BThi + (size_t)(n0 + rb) * K + kb + ch * 8);
        short8 bl = *(const short8*)(BTlo + (size_t)(n0 + rb) * K + kb + ch * 8);
        *(short8*)(Bhi + rb * 128 + swb) = bh;
        *(short8*)(Blo + rb * 128 + swb) = bl;
      }
    }
    __syncthreads();
    #pragma unroll
    for (int kt = 0; kt < 2; ++kt){
      int klb = (kt * 32 + lhi * 8) * 2;
      int rowA = wr * 16 + l15;
      int swA = klb ^ ((rowA & 7) << 4);
      short8 ah = *(const short8*)(Ahi + rowA * 128 + swA);
      short8 al = *(const short8*)(Alo + rowA * 128 + swA);
      #pragma unroll
      for (int n = 0; n < 2; ++n){
        int rowB = wc * 32 + n * 16 + l15;
        int swB = klb ^ ((rowB & 7) << 4);
        short8 bh = *(const short8*)(Bhi + rowB * 128 + swB);
        short8 bl = *(const short8*)(Blo + rowB * 128 + swB);
        acc[n] = __builtin_amdgcn_mfma_f32_16x16x32_bf16(ah, bh, acc[n], 0, 0, 0);
        acc[n] = __builtin_amdgcn_mfma_f32_16x16x32_bf16(ah, bl, acc[n], 0, 0, 0);
        acc[n] = __builtin_amdgcn_mfma_f32_16x16x32_bf16(al, bh, acc[n], 0, 0, 0);
      }
    }
    __syncthreads();
  }
  // ---- epilogue: transposed bf16 write + per-row score-dot partials ----
  float sp[4] = {0.f, 0.f, 0.f, 0.f};
  float dp[4] = {0.f, 0.f, 0.f, 0.f};
  #pragma unroll
  for (int n = 0; n < 2; ++n){
    int col = n0 + wc * 32 + n * 16 + l15;
    float asv = as[col], adv = ad[col];
    ushort4v o;
    #pragma unroll
    for (int rr = 0; rr < 4; ++rr){
      float v = acc[n][rr];
      o[rr] = f2bf(v);
      sp[rr] += v * asv;
      dp[rr] += v * adv;
    }
    *(ushort4v*)(VTh + (size_t)col * GN + i0 + wr * 16 + lhi * 4) = o;
  }
  #pragma unroll
  for (int off = 1; off < 16; off <<= 1){
    #pragma unroll
    for (int rr = 0; rr < 4; ++rr){
      sp[rr] += __shfl_xor(sp[rr], off);
      dp[rr] += __shfl_xor(dp[rr], off);
    }
  }
  if (l15 == 0){
    #pragma unroll
    for (int rr = 0; rr < 4; ++rr){
      int r = wr * 16 + lhi * 4 + rr;
      red[r][wc][0] = sp[rr];
      red[r][wc][1] = dp[rr];
    }
  }
  __syncthreads();
  if (tid < 64){
    int r = tid >> 1, sel = tid & 1;
    float v = red[r][0][sel] + red[r][1][sel];
    spart[((size_t)sel * 4 + blockIdx.x) * GN + i0 + r] = v;
  }
}

// ----- fused PV: ss/sd from spart (sfin folded in); P built once; 1 V buf --
__global__ __launch_bounds__(128) void gat_pv(const u64* __restrict__ mask,
                                              const float* __restrict__ spart,
                                              const ushort_t* __restrict__ VTh,
                                              float* __restrict__ partial,
                                              float* __restrict__ szb){
  __shared__ char Blds[20480];
  __shared__ char Plds[32 * 80];
  __shared__ float wsum[2][32];
  __shared__ float sdl[KSTEPS * 32];
  const int tid = threadIdx.x;
  const int lane = tid & 63, w = tid >> 6;
  const int l15 = lane & 15, lhi = lane >> 4;
  const int i0 = blockIdx.x * 32;
  const int kz = blockIdx.y;
  const int ch = tid & 3, c0 = tid >> 2;
  const int ncol0 = w * 128;

  // ---- sd slice for this chunk (identical summation order) ----
  {
    int jl = tid * 4;
    int j0 = kz * (KSTEPS * 32) + jl;
    floatx4 d = {};
    #pragma unroll
    for (int q = 0; q < 4; ++q){
      floatx4 p = *(const floatx4*)(spart + (size_t)(4 + q) * GN + j0);
      #pragma unroll
      for (int e = 0; e < 4; ++e) d[e] += p[e];
    }
    #pragma unroll
    for (int e = 0; e < 4; ++e) d[e] *= LOG2E;
    *(floatx4*)(sdl + jl) = d;
  }

  const int prow = l15 + ((lhi & 1) << 4);
  const int row = i0 + prow;
  float ssr;
  {
    float s = 0.f;
    #pragma unroll
    for (int q = 0; q < 4; ++q) s += spart[(size_t)q * GN + row];
    ssr = s * LOG2E;
  }
  const int kkb = w * 16 + ((lhi >> 1) << 3);

  u64 mw[8];
  {
    const u64* mr = mask + (size_t)row * 64 + kz * 8;
    #pragma unroll
    for (int q = 0; q < 8; ++q) mw[q] = mr[q];
  }

  floatx4 acc[2][8] = {};
  float srow = 0.f;
  short8 g[8];

  auto GLOAD = [&](int kb){
    const int kbase = (kz * KSTEPS + kb) * 32;
    #pragma unroll
    for (int i = 0; i < 8; ++i){
      int c = c0 + 32 * i;
      g[i] = *(const short8*)(VTh + (size_t)c * GN + kbase + ch * 8);
    }
  };
  auto SWRITE = [&](){
    #pragma unroll
    for (int i = 0; i < 8; ++i){
      int c = c0 + 32 * i;
      *(short8*)(Blds + c * 80 + ch * 16) = g[i];
    }
  };

  GLOAD(0); SWRITE(); __syncthreads();   // covers sdl build too

  for (int kb = 0; kb < KSTEPS; ++kb){
    {
      floatx4 s0 = *(const floatx4*)(sdl + kb * 32 + kkb);
      floatx4 s1 = *(const floatx4*)(sdl + kb * 32 + kkb + 4);
      const int sh = ((kb & 1) << 5) + kkb;
      uint bits = (uint)(mw[kb >> 1] >> sh) & 0xffu;
      short8 pv;
      #pragma unroll
      for (int e = 0; e < 8; ++e){
        float sv = (e < 4) ? s0[e] : s1[e - 4];
        float t = ssr + sv;
        float lr = fmaxf(t, 0.2f * t);
        float p = exp2_(lr);
        p = ((bits >> e) & 1u) ? p : 0.0f;
        srow += p;
        pv[e] = (short)f2bf(p);
      }
      *(short8*)(Plds + prow * 80 + kkb * 2) = pv;
    }
    __syncthreads();

    if (kb + 1 < KSTEPS) GLOAD(kb + 1);

    short8 a0 = *(const short8*)(Plds + l15 * 80 + lhi * 16);
    short8 a1 = *(const short8*)(Plds + (l15 + 16) * 80 + lhi * 16);
    #pragma unroll
    for (int n = 0; n < 8; ++n){
      short8 b = *(const short8*)(Blds + (ncol0 + n * 16 + l15) * 80 + lhi * 16);
      acc[0][n] = __builtin_amdgcn_mfma_f32_16x16x32_bf16(a0, b, acc[0][n], 0, 0, 0);
      acc[1][n] = __builtin_amdgcn_mfma_f32_16x16x32_bf16(a1, b, acc[1][n], 0, 0, 0);
    }
    __syncthreads();
    if (kb + 1 < KSTEPS) SWRITE();
  }

  srow += __shfl_xor(srow, 32);
  if (lane < 32) wsum[w][prow] = srow;
  __syncthreads();
  if (w == 0 && lane < 32)
    szb[(size_t)kz * GN + i0 + lane] = wsum[0][lane] + wsum[1][lane];

  float* pout = partial + (size_t)kz * GN * GH;
  #pragma unroll
  for (int m = 0; m < 2; ++m){
    const int rbase = i0 + m * 16 + lhi * 4;
    #pragma unroll
    for (int n = 0; n < 8; ++n){
      int col = ncol0 + n * 16 + l15;
      #pragma unroll
      for (int rr = 0; rr < 4; ++rr)
        pout[(size_t)(rbase + rr) * GH + col] = acc[m][n][rr];
    }
  }
}

// ---- colfin slice (8 cols) as device fn; math identical to R13 colfin ----
__device__ __forceinline__ void colfin_slice(const float* __restrict__ part,
                                             const float* __restrict__ partm2,
                                             const float* __restrict__ gamma,
                                             const float* __restrict__ beta,
                                             float* __restrict__ scale,
                                             float* __restrict__ bias,
                                             int slice, double (*red)[9]){
  const int tid = threadIdx.x;
  const int cl = tid & 7, g = tid >> 3;   // g: 0..31
  const int c = slice * 8 + cl;
  double S = 0.0;
  for (int b = g * 32; b < g * 32 + 32; ++b) S += (double)part[(size_t)b * GH + c];
  red[g][cl] = S;
  __syncthreads();
  double mean = 0.0;
  #pragma unroll
  for (int q = 0; q < 32; ++q) mean += red[q][cl];
  mean *= (1.0 / 4096.0);
  double M2 = 0.0;
  for (int b = g * 32; b < g * 32 + 32; ++b){
    double mb = (double)part[(size_t)b * GH + c] * 0.25;
    double dd = mb - mean;
    M2 += (double)partm2[(size_t)b * GH + c] + 4.0 * dd * dd;
  }
  __syncthreads();
  red[g][cl] = M2;
  __syncthreads();
  if (g == 0){
    double M2t = 0.0;
    #pragma unroll
    for (int q = 0; q < 32; ++q) M2t += red[q][cl];
    double var = M2t * (1.0 / 4096.0);
    float sc = gamma[c] * (float)(1.0 / sqrt(var + 1e-5));
    scale[c] = sc;
    bias[c] = beta[c] - (float)mean * sc;
  }
}

#define AGT __HIP_MEMORY_SCOPE_AGENT

// -- combineA (layer 1): chunks->outb + stats; last 32 blocks run colfin ----
__global__ __launch_bounds__(256, 4) void combineA(const float* __restrict__ partial,
                                                   const float* __restrict__ szb,
                                                   float* __restrict__ outb,
                                                   float* __restrict__ part,
                                                   float* __restrict__ partm2,
                                                   const float* __restrict__ gamma,
                                                   const float* __restrict__ beta,
                                                   float* __restrict__ scale,
                                                   float* __restrict__ bias,
                                                   uint* __restrict__ cnt){
  __shared__ float fl[4];
  __shared__ float sm[4][GH];
  __shared__ double redf[32][9];
  __shared__ uint rord;
  const int tid = threadIdx.x;
  const int b = blockIdx.x;
  const int r0 = b * 4;
  if (tid < 4){
    int row = r0 + tid;
    float lsum = 0.f;
    #pragma unroll
    for (int z = 0; z < 8; ++z) lsum += szb[(size_t)z * GN + row];
    fl[tid] = lsum > 0.f ? 1.0f / lsum : 0.f;
  }
  __syncthreads();
  const int r = tid >> 6;
  const int c4 = (tid & 63) * 4;
  const size_t idx = (size_t)(r0 + r) * GH + c4;
  floatx4 x = {};
  #pragma unroll
  for (int z = 0; z < 8; ++z){
    floatx4 p = *(const floatx4*)(partial + (size_t)z * GN * GH + idx);
    #pragma unroll
    for (int e = 0; e < 4; ++e) x[e] += p[e];
  }
  const float linv = fl[r];
  #pragma unroll
  for (int e = 0; e < 4; ++e) x[e] = fmaxf(x[e] * linv, 0.0f);
  *(floatx4*)(outb + idx) = x;
  *(floatx4*)(&sm[r][c4]) = x;
  __syncthreads();
  if (tid < 64){
    const int cb = tid * 4;
    floatx4 v0 = *(const floatx4*)(&sm[0][cb]);
    floatx4 v1 = *(const floatx4*)(&sm[1][cb]);
    floatx4 v2 = *(const floatx4*)(&sm[2][cb]);
    floatx4 v3 = *(const floatx4*)(&sm[3][cb]);
    floatx4 s, m2;
    #pragma unroll
    for (int e = 0; e < 4; ++e){
      float sum = v0[e] + v1[e] + v2[e] + v3[e];
      float mu = sum * 0.25f;
      float d0 = v0[e]-mu, d1 = v1[e]-mu, d2 = v2[e]-mu, d3 = v3[e]-mu;
      s[e] = sum;
      m2[e] = d0*d0 + d1*d1 + d2*d2 + d3*d3;
    }
    *(floatx4*)(part + (size_t)b * GH + cb) = s;
    *(floatx4*)(partm2 + (size_t)b * GH + cb) = m2;
  }
  __threadfence();
  __syncthreads();
  if (tid == 0) rord = __hip_atomic_fetch_add(cnt, 1u, __ATOMIC_ACQ_REL, AGT);
  __syncthreads();
  if (rord >= 992u){
    if (tid == 0){
      while (__hip_atomic_load(cnt, __ATOMIC_ACQUIRE, AGT) < 1024u)
        __builtin_amdgcn_s_sleep(8);
    }
    __syncthreads();
    __threadfence();
    colfin_slice(part, partm2, gamma, beta, scale, bias, (int)(rord - 992u), redf);
  }
}

// -- combineB (layer 2): stats (no outb), colfin by last 32, then ALL blocks
// apply BN from registers -> dst. Requires all 1024 blocks co-resident (4/CU).
__global__ __launch_bounds__(256, 4) void combineB(const float* __restrict__ partial,
                                                   const float* __restrict__ szb,
                                                   float* __restrict__ part,
                                                   float* __restrict__ partm2,
                                                   const float* __restrict__ gamma,
                                                   const float* __restrict__ beta,
                                                   float* __restrict__ scale,
                                                   float* __restrict__ bias,
                                                   float* __restrict__ dst,
                                                   uint* __restrict__ cnt,
                                                   uint* __restrict__ cnt2){
  __shared__ float fl[4];
  __shared__ float sm[4][GH];
  __shared__ double redf[32][9];
  __shared__ uint rord;
  const int tid = threadIdx.x;
  const int b = blockIdx.x;
  const int r0 = b * 4;
  if (tid < 4){
    int row = r0 + tid;
    float lsum = 0.f;
    #pragma unroll
    for (int z = 0; z < 8; ++z) lsum += szb[(size_t)z * GN + row];
    fl[tid] = lsum > 0.f ? 1.0f / lsum : 0.f;
  }
  __syncthreads();
  const int r = tid >> 6;
  const int c4 = (tid & 63) * 4;
  const size_t idx = (size_t)(r0 + r) * GH + c4;
  floatx4 x = {};
  #pragma unroll
  for (int z = 0; z < 8; ++z){
    floatx4 p = *(const floatx4*)(partial + (size_t)z * GN * GH + idx);
    #pragma unroll
    for (int e = 0; e < 4; ++e) x[e] += p[e];
  }
  const float linv = fl[r];
  #pragma unroll
  for (int e = 0; e < 4; ++e) x[e] = fmaxf(x[e] * linv, 0.0f);
  *(floatx4*)(&sm[r][c4]) = x;
  __syncthreads();
  if (tid < 64){
    const int cb = tid * 4;
    floatx4 v0 = *(const floatx4*)(&sm[0][cb]);
    floatx4 v1 = *(const floatx4*)(&sm[1][cb]);
    floatx4 v2 = *(const floatx4*)(&sm[2][cb]);
    floatx4 v3 = *(const floatx4*)(&sm[3][cb]);
    floatx4 s, m2;
    #pragma unroll
    for (int e = 0; e < 4; ++e){
      float sum = v0[e] + v1[e] + v2[e] + v3[e];
      float mu = sum * 0.25f;
      float d0 = v0[e]-mu, d1 = v1[e]-mu, d2 = v2[e]-mu, d3 = v3[e]-mu;
      s[e] = sum;
      m2[e] = d0*d0 + d1*d1 + d2*d2 + d3*d3;
    }
    *(floatx4*)(part + (size_t)b * GH + cb) = s;
    *(floatx4*)(partm2 + (size_t)b * GH + cb) = m2;
  }
  __threadfence();
  __syncthreads();
  if (tid == 0) rord = __hip_atomic_fetch_add(cnt, 1u, __ATOMIC_ACQ_REL, AGT);
  __syncthreads();
  if (rord >= 992u){
    if (tid == 0){
      while (__hip_atomic_load(cnt, __ATOMIC_ACQUIRE, AGT) < 1024u)
        __builtin_amdgcn_s_sleep(8);
    }
    __syncthreads();
    __threadfence();
    colfin_slice(part, partm2, gamma, beta, scale, bias, (int)(rord - 992u), redf);
    __threadfence();
    __syncthreads();
    if (tid == 0) __hip_atomic_fetch_add(cnt2, 1u, __ATOMIC_ACQ_REL, AGT);
  }
  if (tid == 0){
    while (__hip_atomic_load(cnt2, __ATOMIC_ACQUIRE, AGT) < 32u)
      __builtin_amdgcn_s_sleep(8);
  }
  __syncthreads();
  __threadfence();
  floatx4 sc = *(const floatx4*)(scale + c4);
  floatx4 bi = *(const floatx4*)(bias + c4);
  #pragma unroll
  for (int e = 0; e < 4; ++e) x[e] = x[e] * sc[e] + bi[e];
  *(floatx4*)(dst + idx) = x;
}

extern "C" void kernel_launch(void* const* d_in, const int* in_sizes, int n_in,
                              void* d_out, int out_size, void* d_ws, size_t ws_size,
                              hipStream_t stream) {
  const float* x      = (const float*)d_in[0];
  const int*   adj    = (const int*)d_in[1];
  const float* W1     = (const float*)d_in[2];
  const float* a1s    = (const float*)d_in[3];
  const float* a1d    = (const float*)d_in[4];
  const float* g1     = (const float*)d_in[5];
  const float* b1     = (const float*)d_in[6];
  const float* W2     = (const float*)d_in[7];
  const float* a2s    = (const float*)d_in[8];
  const float* a2d    = (const float*)d_in[9];
  const float* g2     = (const float*)d_in[10];
  const float* b2     = (const float*)d_in[11];

  char* w = (char*)d_ws;
  auto alloc = [&](size_t bytes){ void* p = (void*)w; w += (bytes + 255) & ~(size_t)255; return p; };
  u64*      mask   = (u64*)alloc((size_t)GN * 64 * 8);          // 2 MB
  ushort_t* W1Th   = (ushort_t*)alloc((size_t)GH * 512 * 2);
  ushort_t* W1Tl   = (ushort_t*)alloc((size_t)GH * 512 * 2);
  ushort_t* W2Th   = (ushort_t*)alloc((size_t)GH * GH * 2);
  ushort_t* W2Tl   = (ushort_t*)alloc((size_t)GH * GH * 2);
  ushort_t* VThb   = (ushort_t*)alloc((size_t)GH * GN * 2);     // 2 MB
  float*    outb   = (float*)alloc((size_t)GN * GH * 4);        // 4 MB
  float*    partial= (float*)alloc((size_t)KZ * GN * GH * 4);   // 32 MB
  float*    spart  = (float*)alloc((size_t)2 * 4 * GN * 4);     // 128 KB
  float*    szb    = (float*)alloc((size_t)KZ * GN * 4);
  float*    part   = (float*)alloc((size_t)1024 * GH * 4);      // 1 MB
  float*    partm2 = (float*)alloc((size_t)1024 * GH * 4);      // 1 MB
  float*    scale  = (float*)alloc(GH * 4);
  float*    bias   = (float*)alloc(GH * 4);
  uint*     flags  = (uint*)alloc(64);

  hipMemsetAsync(flags, 0, 64, stream);

  prep<<<1024 + 192, 256, 0, stream>>>(adj, mask, W1, W1Th, W1Tl, W2, W2Th, W2Tl);

  // ---- layer 1 ----
  gemm_split<false><<<dim3(4, 128), 256, 0, stream>>>(x, W1Th, W1Tl, nullptr, nullptr,
                                                      a1s, a1d, VThb, spart, 512);
  gat_pv<<<dim3(GN/32, KZ), 128, 0, stream>>>(mask, spart, VThb, partial, szb);
  combineA<<<1024, 256, 0, stream>>>(partial, szb, outb, part, partm2,
                                     g1, b1, scale, bias, flags + 0);

  // ---- layer 2 (BN of layer 1 folded into A staging) ----
  gemm_split<true><<<dim3(4, 128), 256, 0, stream>>>(outb, W2Th, W2Tl, scale, bias,
                                                     a2s, a2d, VThb, spart, 256);
  gat_pv<<<dim3(GN/32, KZ), 128, 0, stream>>>(mask, spart, VThb, partial, szb);
  combineB<<<1024, 256, 0, stream>>>(partial, szb, part, partm2,
                                     g2, b2, scale, bias, (float*)d_out,
                                     flags + 1, flags + 2);
}

// Round 15
// 122.448 us; speedup vs baseline: 5.0946x; 5.0946x over previous
//
#include <hip/hip_runtime.h>

#define LOG2E 1.4426950408889634f

typedef unsigned long long u64;
typedef unsigned int uint;
typedef unsigned short ushort_t;
typedef __attribute__((ext_vector_type(8))) short short8;
typedef __attribute__((ext_vector_type(4))) float floatx4;
typedef __attribute__((ext_vector_type(4))) int intx4;
typedef __attribute__((ext_vector_type(4))) unsigned short ushort4v;

#define GN 4096
#define GH 256
#define KZ 8
#define KSTEPS 16   // K-steps of 32 neighbors per block: KZ*KSTEPS*32 = 4096

__device__ __forceinline__ ushort_t f2bf(float f){
  uint u = __float_as_uint(f);
  u += 0x7FFFu + ((u >> 16) & 1u);
  return (ushort_t)(u >> 16);
}
__device__ __forceinline__ float bf2f(ushort_t h){
  return __uint_as_float(((uint)h) << 16);
}
__device__ __forceinline__ float exp2_(float x){
#if __has_builtin(__builtin_amdgcn_exp2f)
  return __builtin_amdgcn_exp2f(x);
#else
  return exp2f(x);
#endif
}

// ---- fused prep: blocks 0..1023 pack adj (4 rows each); 1024.. transpose W
__global__ __launch_bounds__(256) void prep(const int* __restrict__ adj,
                                            u64* __restrict__ mask,
                                            const float* __restrict__ W1,
                                            ushort_t* __restrict__ W1h,
                                            ushort_t* __restrict__ W1l,
                                            const float* __restrict__ W2,
                                            ushort_t* __restrict__ W2h,
                                            ushort_t* __restrict__ W2l){
  __shared__ union {
    unsigned char nib[4][1024];
    ushort_t tt[2][32][33];
  } sh;
  const int t = threadIdx.x;
  if (blockIdx.x < 1024){
    const int r0 = blockIdx.x * 4;
    const int* base = adj + (size_t)r0 * GN;
    #pragma unroll
    for (int i = 0; i < 16; ++i){
      int c = i * 256 + t;                 // int4 index within 4 rows
      intx4 v = *(const intx4*)(base + c * 4);
      uint n = (uint)(v[0] > 0) | ((uint)(v[1] > 0) << 1) |
               ((uint)(v[2] > 0) << 2) | ((uint)(v[3] > 0) << 3);
      sh.nib[c >> 10][c & 1023] = (unsigned char)n;
    }
    __syncthreads();
    {
      int r = t >> 6, wi = t & 63;
      const u64* p = (const u64*)sh.nib[r];
      u64 x0 = p[wi * 2], x1 = p[wi * 2 + 1];
      auto comp = [](u64 x)->u64{
        x = (x | (x >> 4))  & 0x00FF00FF00FF00FFULL;
        x = (x | (x >> 8))  & 0x0000FFFF0000FFFFULL;
        x = (x | (x >> 16)) & 0x00000000FFFFFFFFULL;
        return x;
      };
      mask[(size_t)(r0 + r) * 64 + wi] = comp(x0) | (comp(x1) << 32);
    }
    return;
  }
  int b = blockIdx.x - 1024;
  const float* in; ushort_t* hi; ushort_t* lo; int R, idx;
  if (b < 128){ in = W1; hi = W1h; lo = W1l; R = 512; idx = b; }
  else        { in = W2; hi = W2h; lo = W2l; R = 256; idx = b - 128; }
  const int C = GH;
  const int bx = idx & 7, by = idx >> 3;
  const int i0 = by * 32, j0 = bx * 32;
  const int r = t >> 3, c4 = (t & 7) * 4;
  floatx4 v = *(const floatx4*)(in + (size_t)(i0 + r) * C + j0 + c4);
  #pragma unroll
  for (int e = 0; e < 4; ++e){
    ushort_t h = f2bf(v[e]);
    sh.tt[0][r][c4 + e] = h;
    sh.tt[1][r][c4 + e] = f2bf(v[e] - bf2f(h));
  }
  __syncthreads();
  ushort4v oh, ol;
  #pragma unroll
  for (int e = 0; e < 4; ++e){ oh[e] = sh.tt[0][c4 + e][r]; ol[e] = sh.tt[1][c4 + e][r]; }
  *(ushort4v*)(hi + (size_t)(j0 + r) * R + i0 + c4) = oh;
  *(ushort4v*)(lo + (size_t)(j0 + r) * R + i0 + c4) = ol;
}

// --- split-bf16 GEMM + fused epilogue: writes bf16 V^T and score-dot partials.
template<bool BN>
__global__ __launch_bounds__(256) void gemm_split(const float* __restrict__ A,
                                                  const ushort_t* __restrict__ BThi,
                                                  const ushort_t* __restrict__ BTlo,
                                                  const float* __restrict__ bnsc,
                                                  const float* __restrict__ bnbi,
                                                  const float* __restrict__ as,
                                                  const float* __restrict__ ad,
                                                  ushort_t* __restrict__ VTh,
                                                  float* __restrict__ spart,
                                                  int K){
  __shared__ short8 AhiV[32 * 8];
  __shared__ short8 AloV[32 * 8];
  __shared__ short8 BhiV[64 * 8];
  __shared__ short8 BloV[64 * 8];
  __shared__ float red[32][2][2];
  char* Ahi = (char*)AhiV; char* Alo = (char*)AloV;
  char* Bhi = (char*)BhiV; char* Blo = (char*)BloV;
  const int tid = threadIdx.x;
  const int i0 = blockIdx.y * 32, n0 = blockIdx.x * 64;
  const int lane = tid & 63, wave = tid >> 6;
  const int wr = wave & 1, wc = wave >> 1;
  const int l15 = lane & 15, lhi = lane >> 4;
  const int rs = tid >> 3, ch = tid & 7;
  floatx4 acc[2] = {};
  for (int kb = 0; kb < K; kb += 64){
    {
      int r = rs;
      floatx4 f0 = *(const floatx4*)(A + (size_t)(i0 + r) * K + kb + ch * 8);
      floatx4 f1 = *(const floatx4*)(A + (size_t)(i0 + r) * K + kb + ch * 8 + 4);
      if constexpr (BN){
        floatx4 sc0 = *(const floatx4*)(bnsc + kb + ch * 8);
        floatx4 sc1 = *(const floatx4*)(bnsc + kb + ch * 8 + 4);
        floatx4 bi0 = *(const floatx4*)(bnbi + kb + ch * 8);
        floatx4 bi1 = *(const floatx4*)(bnbi + kb + ch * 8 + 4);
        #pragma unroll
        for (int e = 0; e < 4; ++e){
          f0[e] = f0[e] * sc0[e] + bi0[e];
          f1[e] = f1[e] * sc1[e] + bi1[e];
        }
      }
      short8 ah, al;
      #pragma unroll
      for (int e = 0; e < 4; ++e){
        ushort_t h0 = f2bf(f0[e]); ah[e] = (short)h0; al[e] = (short)f2bf(f0[e] - bf2f(h0));
        ushort_t h1 = f2bf(f1[e]); ah[e+4] = (short)h1; al[e+4] = (short)f2bf(f1[e] - bf2f(h1));
      }
      const int sw = (ch * 16) ^ ((r & 7) << 4);
      *(short8*)(Ahi + r * 128 + sw) = ah;
      *(short8*)(Alo + r * 128 + sw) = al;
      #pragma unroll
      for (int q = 0; q < 2; ++q){
        int rb = rs + q * 32;
        const int swb = (ch * 16) ^ ((rb & 7) << 4);
        short8 bh = *(const short8*)(BThi + (size_t)(n0 + rb) * K + kb + ch * 8);
        short8 bl = *(const short8*)(BTlo + (size_t)(n0 + rb) * K + kb + ch * 8);
        *(short8*)(Bhi + rb * 128 + swb) = bh;
        *(short8*)(Blo + rb * 128 + swb) = bl;
      }
    }
    __syncthreads();
    #pragma unroll
    for (int kt = 0; kt < 2; ++kt){
      int klb = (kt * 32 + lhi * 8) * 2;
      int rowA = wr * 16 + l15;
      int swA = klb ^ ((rowA & 7) << 4);
      short8 ah = *(const short8*)(Ahi + rowA * 128 + swA);
      short8 al = *(const short8*)(Alo + rowA * 128 + swA);
      #pragma unroll
      for (int n = 0; n < 2; ++n){
        int rowB = wc * 32 + n * 16 + l15;
        int swB = klb ^ ((rowB & 7) << 4);
        short8 bh = *(const short8*)(Bhi + rowB * 128 + swB);
        short8 bl = *(const short8*)(Blo + rowB * 128 + swB);
        acc[n] = __builtin_amdgcn_mfma_f32_16x16x32_bf16(ah, bh, acc[n], 0, 0, 0);
        acc[n] = __builtin_amdgcn_mfma_f32_16x16x32_bf16(ah, bl, acc[n], 0, 0, 0);
        acc[n] = __builtin_amdgcn_mfma_f32_16x16x32_bf16(al, bh, acc[n], 0, 0, 0);
      }
    }
    __syncthreads();
  }
  // ---- epilogue: transposed bf16 write + per-row score-dot partials ----
  float sp[4] = {0.f, 0.f, 0.f, 0.f};
  float dp[4] = {0.f, 0.f, 0.f, 0.f};
  #pragma unroll
  for (int n = 0; n < 2; ++n){
    int col = n0 + wc * 32 + n * 16 + l15;
    float asv = as[col], adv = ad[col];
    ushort4v o;
    #pragma unroll
    for (int rr = 0; rr < 4; ++rr){
      float v = acc[n][rr];
      o[rr] = f2bf(v);
      sp[rr] += v * asv;
      dp[rr] += v * adv;
    }
    *(ushort4v*)(VTh + (size_t)col * GN + i0 + wr * 16 + lhi * 4) = o;
  }
  #pragma unroll
  for (int off = 1; off < 16; off <<= 1){
    #pragma unroll
    for (int rr = 0; rr < 4; ++rr){
      sp[rr] += __shfl_xor(sp[rr], off);
      dp[rr] += __shfl_xor(dp[rr], off);
    }
  }
  if (l15 == 0){
    #pragma unroll
    for (int rr = 0; rr < 4; ++rr){
      int r = wr * 16 + lhi * 4 + rr;
      red[r][wc][0] = sp[rr];
      red[r][wc][1] = dp[rr];
    }
  }
  __syncthreads();
  if (tid < 64){
    int r = tid >> 1, sel = tid & 1;
    float v = red[r][0][sel] + red[r][1][sel];
    spart[((size_t)sel * 4 + blockIdx.x) * GN + i0 + r] = v;
  }
}

// ----- fused PV: ss/sd from spart (sfin folded in); P built once; 1 V buf --
__global__ __launch_bounds__(128) void gat_pv(const u64* __restrict__ mask,
                                              const float* __restrict__ spart,
                                              const ushort_t* __restrict__ VTh,
                                              float* __restrict__ partial,
                                              float* __restrict__ szb){
  __shared__ char Blds[20480];
  __shared__ char Plds[32 * 80];
  __shared__ float wsum[2][32];
  __shared__ float sdl[KSTEPS * 32];
  const int tid = threadIdx.x;
  const int lane = tid & 63, w = tid >> 6;
  const int l15 = lane & 15, lhi = lane >> 4;
  const int i0 = blockIdx.x * 32;
  const int kz = blockIdx.y;
  const int ch = tid & 3, c0 = tid >> 2;
  const int ncol0 = w * 128;

  // ---- sd slice for this chunk (identical summation order) ----
  {
    int jl = tid * 4;
    int j0 = kz * (KSTEPS * 32) + jl;
    floatx4 d = {};
    #pragma unroll
    for (int q = 0; q < 4; ++q){
      floatx4 p = *(const floatx4*)(spart + (size_t)(4 + q) * GN + j0);
      #pragma unroll
      for (int e = 0; e < 4; ++e) d[e] += p[e];
    }
    #pragma unroll
    for (int e = 0; e < 4; ++e) d[e] *= LOG2E;
    *(floatx4*)(sdl + jl) = d;
  }

  const int prow = l15 + ((lhi & 1) << 4);
  const int row = i0 + prow;
  float ssr;
  {
    float s = 0.f;
    #pragma unroll
    for (int q = 0; q < 4; ++q) s += spart[(size_t)q * GN + row];
    ssr = s * LOG2E;
  }
  const int kkb = w * 16 + ((lhi >> 1) << 3);

  u64 mw[8];
  {
    const u64* mr = mask + (size_t)row * 64 + kz * 8;
    #pragma unroll
    for (int q = 0; q < 8; ++q) mw[q] = mr[q];
  }

  floatx4 acc[2][8] = {};
  float srow = 0.f;
  short8 g[8];

  auto GLOAD = [&](int kb){
    const int kbase = (kz * KSTEPS + kb) * 32;
    #pragma unroll
    for (int i = 0; i < 8; ++i){
      int c = c0 + 32 * i;
      g[i] = *(const short8*)(VTh + (size_t)c * GN + kbase + ch * 8);
    }
  };
  auto SWRITE = [&](){
    #pragma unroll
    for (int i = 0; i < 8; ++i){
      int c = c0 + 32 * i;
      *(short8*)(Blds + c * 80 + ch * 16) = g[i];
    }
  };

  GLOAD(0); SWRITE(); __syncthreads();   // covers sdl build too

  for (int kb = 0; kb < KSTEPS; ++kb){
    {
      floatx4 s0 = *(const floatx4*)(sdl + kb * 32 + kkb);
      floatx4 s1 = *(const floatx4*)(sdl + kb * 32 + kkb + 4);
      const int sh = ((kb & 1) << 5) + kkb;
      uint bits = (uint)(mw[kb >> 1] >> sh) & 0xffu;
      short8 pv;
      #pragma unroll
      for (int e = 0; e < 8; ++e){
        float sv = (e < 4) ? s0[e] : s1[e - 4];
        float t = ssr + sv;
        float lr = fmaxf(t, 0.2f * t);
        float p = exp2_(lr);
        p = ((bits >> e) & 1u) ? p : 0.0f;
        srow += p;
        pv[e] = (short)f2bf(p);
      }
      *(short8*)(Plds + prow * 80 + kkb * 2) = pv;
    }
    __syncthreads();

    if (kb + 1 < KSTEPS) GLOAD(kb + 1);

    short8 a0 = *(const short8*)(Plds + l15 * 80 + lhi * 16);
    short8 a1 = *(const short8*)(Plds + (l15 + 16) * 80 + lhi * 16);
    #pragma unroll
    for (int n = 0; n < 8; ++n){
      short8 b = *(const short8*)(Blds + (ncol0 + n * 16 + l15) * 80 + lhi * 16);
      acc[0][n] = __builtin_amdgcn_mfma_f32_16x16x32_bf16(a0, b, acc[0][n], 0, 0, 0);
      acc[1][n] = __builtin_amdgcn_mfma_f32_16x16x32_bf16(a1, b, acc[1][n], 0, 0, 0);
    }
    __syncthreads();
    if (kb + 1 < KSTEPS) SWRITE();
  }

  srow += __shfl_xor(srow, 32);
  if (lane < 32) wsum[w][prow] = srow;
  __syncthreads();
  if (w == 0 && lane < 32)
    szb[(size_t)kz * GN + i0 + lane] = wsum[0][lane] + wsum[1][lane];

  float* pout = partial + (size_t)kz * GN * GH;
  #pragma unroll
  for (int m = 0; m < 2; ++m){
    const int rbase = i0 + m * 16 + lhi * 4;
    #pragma unroll
    for (int n = 0; n < 8; ++n){
      int col = ncol0 + n * 16 + l15;
      #pragma unroll
      for (int rr = 0; rr < 4; ++rr)
        pout[(size_t)(rbase + rr) * GH + col] = acc[m][n][rr];
    }
  }
}

// -- combine: sum chunks, 1/l, ReLU, outb, BN strip stats ------------------
__global__ __launch_bounds__(256) void combine_colpart(const float* __restrict__ partial,
                                                       const float* __restrict__ szb,
                                                       float* __restrict__ outb,
                                                       float* __restrict__ part,
                                                       float* __restrict__ partm2){
  __shared__ float fl[4];
  __shared__ float sm[4][GH];
  const int tid = threadIdx.x;
  const int b = blockIdx.x;          // 0..1023, strip of 4 rows
  const int r0 = b * 4;
  if (tid < 4){
    int row = r0 + tid;
    float lsum = 0.f;
    #pragma unroll
    for (int z = 0; z < 8; ++z) lsum += szb[(size_t)z * GN + row];
    fl[tid] = lsum > 0.f ? 1.0f / lsum : 0.f;
  }
  __syncthreads();
  const int r = tid >> 6;            // 0..3 (row within strip)
  const int c4 = (tid & 63) * 4;
  const size_t idx = (size_t)(r0 + r) * GH + c4;
  floatx4 x = {};
  #pragma unroll
  for (int z = 0; z < 8; ++z){
    floatx4 p = *(const floatx4*)(partial + (size_t)z * GN * GH + idx);
    #pragma unroll
    for (int e = 0; e < 4; ++e) x[e] += p[e];
  }
  const float linv = fl[r];
  #pragma unroll
  for (int e = 0; e < 4; ++e) x[e] = fmaxf(x[e] * linv, 0.0f);
  *(floatx4*)(outb + idx) = x;
  *(floatx4*)(&sm[r][c4]) = x;
  __syncthreads();
  if (tid < 64){
    const int cb = tid * 4;
    floatx4 v0 = *(const floatx4*)(&sm[0][cb]);
    floatx4 v1 = *(const floatx4*)(&sm[1][cb]);
    floatx4 v2 = *(const floatx4*)(&sm[2][cb]);
    floatx4 v3 = *(const floatx4*)(&sm[3][cb]);
    floatx4 s, m2;
    #pragma unroll
    for (int e = 0; e < 4; ++e){
      float sum = v0[e] + v1[e] + v2[e] + v3[e];
      float mu = sum * 0.25f;
      float d0 = v0[e]-mu, d1 = v1[e]-mu, d2 = v2[e]-mu, d3 = v3[e]-mu;
      s[e] = sum;
      m2[e] = d0*d0 + d1*d1 + d2*d2 + d3*d3;
    }
    *(floatx4*)(part + (size_t)b * GH + cb) = s;
    *(floatx4*)(partm2 + (size_t)b * GH + cb) = m2;
  }
}

// ---- combine strip stats (Chan, f64) -> scale/bias; 32 blocks x 8 cols ---
__global__ __launch_bounds__(256) void colfin(const float* __restrict__ part,
                                              const float* __restrict__ partm2,
                                              const float* __restrict__ gamma,
                                              const float* __restrict__ beta,
                                              float* __restrict__ scale,
                                              float* __restrict__ bias){
  __shared__ double red[32][9];
  const int cl = threadIdx.x & 7, g = threadIdx.x >> 3;   // g: 0..31
  const int c = blockIdx.x * 8 + cl;
  double S = 0.0;
  for (int b = g * 32; b < g * 32 + 32; ++b) S += (double)part[(size_t)b * GH + c];
  red[g][cl] = S;
  __syncthreads();
  double mean = 0.0;
  #pragma unroll
  for (int q = 0; q < 32; ++q) mean += red[q][cl];
  mean *= (1.0 / 4096.0);
  double M2 = 0.0;
  for (int b = g * 32; b < g * 32 + 32; ++b){
    double mb = (double)part[(size_t)b * GH + c] * 0.25;
    double dd = mb - mean;
    M2 += (double)partm2[(size_t)b * GH + c] + 4.0 * dd * dd;
  }
  __syncthreads();
  red[g][cl] = M2;
  __syncthreads();
  if (g == 0){
    double M2t = 0.0;
    #pragma unroll
    for (int q = 0; q < 32; ++q) M2t += red[q][cl];
    double var = M2t * (1.0 / 4096.0);
    float sc = gamma[c] * (float)(1.0 / sqrt(var + 1e-5));
    scale[c] = sc;
    bias[c] = beta[c] - (float)mean * sc;
  }
}

// ------------------- apply BN: h*scale + bias -> f32 (final output) -------
__global__ __launch_bounds__(256) void bnapply(const float* __restrict__ outb,
                                               const float* __restrict__ scale,
                                               const float* __restrict__ bias,
                                               float* __restrict__ dst){
  const int base = (blockIdx.x * 256 + threadIdx.x) * 4;
  const int c = base & (GH - 1);
  floatx4 v = *(const floatx4*)(outb + base);
  floatx4 s = *(const floatx4*)(scale + c);
  floatx4 b = *(const floatx4*)(bias + c);
  #pragma unroll
  for (int e = 0; e < 4; ++e) v[e] = v[e] * s[e] + b[e];
  *(floatx4*)(dst + base) = v;
}

extern "C" void kernel_launch(void* const* d_in, const int* in_sizes, int n_in,
                              void* d_out, int out_size, void* d_ws, size_t ws_size,
                              hipStream_t stream) {
  const float* x      = (const float*)d_in[0];
  const int*   adj    = (const int*)d_in[1];
  const float* W1     = (const float*)d_in[2];
  const float* a1s    = (const float*)d_in[3];
  const float* a1d    = (const float*)d_in[4];
  const float* g1     = (const float*)d_in[5];
  const float* b1     = (const float*)d_in[6];
  const float* W2     = (const float*)d_in[7];
  const float* a2s    = (const float*)d_in[8];
  const float* a2d    = (const float*)d_in[9];
  const float* g2     = (const float*)d_in[10];
  const float* b2     = (const float*)d_in[11];

  char* w = (char*)d_ws;
  auto alloc = [&](size_t bytes){ void* p = (void*)w; w += (bytes + 255) & ~(size_t)255; return p; };
  u64*      mask   = (u64*)alloc((size_t)GN * 64 * 8);          // 2 MB
  ushort_t* W1Th   = (ushort_t*)alloc((size_t)GH * 512 * 2);
  ushort_t* W1Tl   = (ushort_t*)alloc((size_t)GH * 512 * 2);
  ushort_t* W2Th   = (ushort_t*)alloc((size_t)GH * GH * 2);
  ushort_t* W2Tl   = (ushort_t*)alloc((size_t)GH * GH * 2);
  ushort_t* VThb   = (ushort_t*)alloc((size_t)GH * GN * 2);     // 2 MB
  float*    outb   = (float*)alloc((size_t)GN * GH * 4);        // 4 MB
  float*    partial= (float*)alloc((size_t)KZ * GN * GH * 4);   // 32 MB
  float*    spart  = (float*)alloc((size_t)2 * 4 * GN * 4);     // 128 KB
  float*    szb    = (float*)alloc((size_t)KZ * GN * 4);
  float*    part   = (float*)alloc((size_t)1024 * GH * 4);      // 1 MB
  float*    partm2 = (float*)alloc((size_t)1024 * GH * 4);      // 1 MB
  float*    scale  = (float*)alloc(GH * 4);
  float*    bias   = (float*)alloc(GH * 4);

  prep<<<1024 + 192, 256, 0, stream>>>(adj, mask, W1, W1Th, W1Tl, W2, W2Th, W2Tl);

  // ---- layer 1 ----
  gemm_split<false><<<dim3(4, 128), 256, 0, stream>>>(x, W1Th, W1Tl, nullptr, nullptr,
                                                      a1s, a1d, VThb, spart, 512);
  gat_pv<<<dim3(GN/32, KZ), 128, 0, stream>>>(mask, spart, VThb, partial, szb);
  combine_colpart<<<1024, 256, 0, stream>>>(partial, szb, outb, part, partm2);
  colfin<<<32, 256, 0, stream>>>(part, partm2, g1, b1, scale, bias);

  // ---- layer 2 (BN of layer 1 folded into A staging) ----
  gemm_split<true><<<dim3(4, 128), 256, 0, stream>>>(outb, W2Th, W2Tl, scale, bias,
                                                     a2s, a2d, VThb, spart, 256);
  gat_pv<<<dim3(GN/32, KZ), 128, 0, stream>>>(mask, spart, VThb, partial, szb);
  combine_colpart<<<1024, 256, 0, stream>>>(partial, szb, outb, part, partm2);
  colfin<<<32, 256, 0, stream>>>(part, partm2, g2, b2, scale, bias);
  bnapply<<<1024, 256, 0, stream>>>(outb, scale, bias, (float*)d_out);
}